// Round 9
// baseline (188.973 us; speedup 1.0000x reference)
//
#include <hip/hip_runtime.h>
#include <hip/hip_bf16.h>

// Problem constants
#define E_   16
#define B_   4096
#define DX_  128
#define DC_  64
#define DIN_ 192
#define DH_  1024
#define DO_  128

#define BM 256
#define KC 64
#define NCHUNK 16
#define NT 1024             // 16 waves = 4 waves/SIMD, unified VGPR cap 128

// LDS (shorts): W1B[2] | W2B[2] | HB[2] = 144 KB
#define W1B_OFF 0
#define W1B_STR 12288   // [64][192] bf16, swizzled image (24 KB)
#define W2B_OFF 24576
#define W2B_STR 8192    // [128][64] bf16, swizzled (16 KB)
#define HB_OFF  40960
#define HB_STR  16384   // [256][64] bf16, swizzled (32 KB)

#define NW1U2 (E_ * DH_ * DIN_ / 4)   // 786432 8B-units of bf16 W1
#define NW2U2 (E_ * DO_ * DH_ / 4)    // 524288 8B-units of bf16 W2
#define WS_BYTES ((size_t)(NW1U2 + NW2U2) * 8)   // 10.5 MB

typedef __attribute__((ext_vector_type(4)))  float f32x4;
typedef __attribute__((ext_vector_type(16))) float f32x16;
typedef __attribute__((ext_vector_type(8)))  short bf16x8;

__device__ __forceinline__ unsigned f2bf_u(float f) {
    union { float f; unsigned u; } v; v.f = f;
    return (v.u + 0x7fffu + ((v.u >> 16) & 1u)) >> 16;   // RNE
}
__device__ __forceinline__ uint2 pack4(float4 v) {
    uint2 r;
    r.x = f2bf_u(v.x) | (f2bf_u(v.y) << 16);
    r.y = f2bf_u(v.z) | (f2bf_u(v.w) << 16);
    return r;
}
// XOR-swizzle (proven r2-r7): byte bits 4..6 ^= (row&7); same formula on
// every producer and consumer of each buffer (rule #21).
__device__ __forceinline__ int swz(int r, int S, int cb) {
    return r * S + ((cb ^ ((r & 7) << 4)) >> 1);
}
__device__ __forceinline__ bf16x8 load8cvt(const float* p) {
    float4 a = *(const float4*)p;
    float4 b = *(const float4*)(p + 4);
    bf16x8 r;
    r[0] = (short)f2bf_u(a.x); r[1] = (short)f2bf_u(a.y);
    r[2] = (short)f2bf_u(a.z); r[3] = (short)f2bf_u(a.w);
    r[4] = (short)f2bf_u(b.x); r[5] = (short)f2bf_u(b.y);
    r[6] = (short)f2bf_u(b.z); r[7] = (short)f2bf_u(b.w);
    return r;
}
// async global->LDS, 16 B per lane; LDS dest = wave-uniform base + lane*16
__device__ __forceinline__ void gld_lds16(const void* g, void* l) {
    __builtin_amdgcn_global_load_lds(
        (const __attribute__((address_space(1))) unsigned int*)g,
        (__attribute__((address_space(3))) unsigned int*)l, 16, 0, 0);
}

// ---- pre-pass: W1 -> bf16 PRE-SWIZZLED per-chunk tiles; W2 -> bf16 linear ----
__global__ __launch_bounds__(256)
void convert_w(const float4* __restrict__ W1, const float4* __restrict__ W2,
               uint2* __restrict__ ws) {
    const int ntot = NW1U2 + NW2U2;
    for (int i = blockIdx.x * 256 + threadIdx.x; i < ntot; i += gridDim.x * 256) {
        if (i < NW1U2) {
            float4 v = W1[i];
            int e  = i / (DH_ * 48);              // 48 8B-units per 192-col row
            int rr = i - e * (DH_ * 48);
            int hr = rr / 48, cu = rr - hr * 48;  // global h-row, unit-col
            int ch = hr >> 6, r = hr & 63;
            int S  = swz(r, DIN_, cu * 8);        // short idx, multiple of 4
            ws[(size_t)(e * 16 + ch) * 3072 + (S >> 2)] = pack4(v);
        } else {
            ws[i] = pack4(W2[i - NW1U2]);         // plain linear bf16 W2
        }
    }
}

template <bool WS>
__global__ __launch_bounds__(NT, 4)
void moe_fused_kernel(const float* __restrict__ x, const float* __restrict__ cond,
                      const float* __restrict__ W1, const float* __restrict__ b1,
                      const float* __restrict__ W2, const float* __restrict__ b2,
                      const uint2* __restrict__ wsw, float* __restrict__ out) {
    __shared__ short LDSU[73728];   // 144 KB -> 1 block/CU

    // XCD swizzle: XCD k owns experts {2k,2k+1}; per-XCD bf16 weights 1.3 MB < L2
    const int bid = blockIdx.x;             // 0..255
    const int xcd = bid & 7;
    const int s   = bid >> 3;
    const int e   = 2 * xcd + (s & 1);
    const int row0 = (s >> 1) * BM;

    const int tid  = threadIdx.x;
    const int w    = tid >> 6;              // wave 0..15
    const int lane = tid & 63;
    const int l31  = lane & 31;
    const int lh   = lane >> 5;             // 0/1: k-half within fragment
    const int mband = w >> 1;               // 0..7: 32-row m band (G1 and G2)
    const int hband = w & 1;                // G1: 32-h tile within chunk
    const int ohalf = w & 1;                // G2: 64-o half

    const char*  ws1b = (const char*)wsw;   // swizzled bf16 W1 tiles
    const uint2* ws2  = wsw + NW1U2 + (size_t)e * (DO_ * DH_ / 4);
    const float4* g1f = (const float4*)(W1 + (size_t)e * DH_ * DIN_);  // fallback
    const float*  g2f = W2 + (size_t)e * DO_ * DH_;

    // ---- xcreg: B-frags of XC rows mband*32+l31 (32x32x16 layout:
    // lane holds XC[m=l31][k = kb*16 + lh*8 + j], j=0..7 contiguous) ----
    bf16x8 xcreg[12];
    {
        const float* xrow = x    + (size_t)(e * B_ + row0 + mband * 32 + l31) * DX_;
        const float* crow = cond + (size_t)(e * B_ + row0 + mband * 32 + l31) * DC_;
#pragma unroll
        for (int kb = 0; kb < 8; ++kb)  xcreg[kb] = load8cvt(xrow + kb * 16 + lh * 8);
#pragma unroll
        for (int kb = 8; kb < 12; ++kb) xcreg[kb] = load8cvt(crow + (kb - 8) * 16 + lh * 8);
    }

    // ---- prologue: stage W1(0) -> W1B[0]; preload r2 = W2(0) ----
    uint2  r2[2]; float4 r2f[2]; float4 r1f[3];
    if constexpr (WS) {
        for (int q = w; q < 24; q += 16)   // 24 x 1KB DMA deposits
            gld_lds16(ws1b + (size_t)(e * 16 + 0) * 24576 + q * 1024 + lane * 16,
                      (char*)&LDSU[W1B_OFF] + q * 1024);
#pragma unroll
        for (int i = 0; i < 2; ++i) {
            int g = tid + NT * i, r = g >> 4, cc = g & 15;
            r2[i] = ws2[r * 256 + cc];
        }
    } else {
#pragma unroll
        for (int i = 0; i < 3; ++i) r1f[i] = g1f[tid + NT * i];   // W1(0)
#pragma unroll
        for (int i = 0; i < 3; ++i) {
            int g = tid + NT * i, r = g / 48, cu = g - r * 48;
            *(uint2*)&LDSU[W1B_OFF + swz(r, DIN_, cu * 8)] = pack4(r1f[i]);
        }
#pragma unroll
        for (int i = 0; i < 3; ++i) r1f[i] = g1f[3072 + tid + NT * i];   // W1(1)
#pragma unroll
        for (int i = 0; i < 2; ++i) {
            int g = tid + NT * i, r = g >> 4, cc = g & 15;
            r2f[i] = *(const float4*)(g2f + (size_t)r * DH_ + cc * 4);
        }
    }
    __syncthreads();    // W1B[0] ready (drains DMA)

    f32x16 acc2[2] = {};   // D2[o-half: 2 o-tiles][this m-band]: 32 VGPR

    // ONE barrier/chunk. Entry invariants: W1B[c&1]=W1(c); r2=W2(c);
    // HB[(c-1)&1]=relu-h(c-1); W2B[(c-1)&1]=W2(c-1).
    for (int c = 0; c < NCHUNK; ++c) {
        const int pc = c & 1, pp = pc ^ 1;

        // (1) pack W2(c) -> W2B[pc]
#pragma unroll
        for (int i = 0; i < 2; ++i) {
            int g = tid + NT * i, r = g >> 4, cc = g & 15;
            uint2 pv; if constexpr (WS) pv = r2[i]; else pv = pack4(r2f[i]);
            *(uint2*)&LDSU[W2B_OFF + pc * W2B_STR + swz(r, KC, cc * 8)] = pv;
        }
        // (2) stage W1(c+1) -> W1B[pp]
        if (c + 1 < NCHUNK) {
            if constexpr (WS) {
                for (int q = w; q < 24; q += 16)
                    gld_lds16(ws1b + (size_t)(e * 16 + c + 1) * 24576 + q * 1024 + lane * 16,
                              (char*)&LDSU[W1B_OFF + pp * W1B_STR] + q * 1024);
            } else {
#pragma unroll
                for (int i = 0; i < 3; ++i) {
                    int g = tid + NT * i, r = g / 48, cu = g - r * 48;
                    *(uint2*)&LDSU[W1B_OFF + pp * W1B_STR + swz(r, DIN_, cu * 8)] = pack4(r1f[i]);
                }
                if (c + 2 < NCHUNK) {
#pragma unroll
                    for (int i = 0; i < 3; ++i) r1f[i] = g1f[(c + 2) * 3072 + tid + NT * i];
                }
            }
        }
        // (3) issue r2 = W2(c+1)
        if (c + 1 < NCHUNK) {
            if constexpr (WS) {
#pragma unroll
                for (int i = 0; i < 2; ++i) {
                    int g = tid + NT * i, r = g >> 4, cc = g & 15;
                    r2[i] = ws2[r * 256 + (c + 1) * 16 + cc];
                }
            } else {
#pragma unroll
                for (int i = 0; i < 2; ++i) {
                    int g = tid + NT * i, r = g >> 4, cc = g & 15;
                    r2f[i] = *(const float4*)(g2f + (size_t)r * DH_ + (c + 1) * KC + cc * 4);
                }
            }
        }

        // (4) G2(c-1): acc2[ot] += W2(c-1)[o,k] x H(c-1)[m,k]  [parity pp]
        if (c > 0) {
#pragma unroll
            for (int kb = 0; kb < 4; ++kb) {
                bf16x8 bH = *(const bf16x8*)&LDSU[HB_OFF + pp * HB_STR +
                                swz(mband * 32 + l31, KC, kb * 32 + lh * 16)];
#pragma unroll
                for (int ot = 0; ot < 2; ++ot) {
                    bf16x8 aW2 = *(const bf16x8*)&LDSU[W2B_OFF + pp * W2B_STR +
                                    swz(ohalf * 64 + ot * 32 + l31, KC, kb * 32 + lh * 16)];
                    acc2[ot] = __builtin_amdgcn_mfma_f32_32x32x16_bf16(aW2, bH, acc2[ot], 0, 0, 0);
                }
            }
        }

        // (5) G1(c): D1[h][m] = W1(c)[h,k] x XC[m,k]  [A from W1B[pc], B=xcreg]
        f32x16 acc1 = {};
#pragma unroll
        for (int kb = 0; kb < 12; ++kb) {
            bf16x8 aW = *(const bf16x8*)&LDSU[W1B_OFF + pc * W1B_STR +
                            swz(hband * 32 + l31, DIN_, kb * 32 + lh * 16)];
            acc1 = __builtin_amdgcn_mfma_f32_32x32x16_bf16(aW, xcreg[kb], acc1, 0, 0, 0);
        }
        // (6) epilogue: HB[pc][m][h] = relu(acc1+b1)
        // D layout (m74/m101): col=m=l31, row=h = (reg&3)+8*(reg>>2)+4*lh
        {
            int m = mband * 32 + l31;
#pragma unroll
            for (int rg = 0; rg < 4; ++rg) {
                float4 b1f = *(const float4*)&b1[e * DH_ + c * KC + hband * 32 + rg * 8 + lh * 4];
                float v0 = fmaxf(acc1[rg * 4 + 0] + b1f.x, 0.f);
                float v1 = fmaxf(acc1[rg * 4 + 1] + b1f.y, 0.f);
                float v2 = fmaxf(acc1[rg * 4 + 2] + b1f.z, 0.f);
                float v3 = fmaxf(acc1[rg * 4 + 3] + b1f.w, 0.f);
                uint2 hv;
                hv.x = f2bf_u(v0) | (f2bf_u(v1) << 16);
                hv.y = f2bf_u(v2) | (f2bf_u(v3) << 16);
                *(uint2*)&LDSU[HB_OFF + pc * HB_STR +
                               swz(m, KC, hband * 64 + rg * 16 + lh * 8)] = hv;
            }
        }

        __syncthreads();   // the ONE barrier (drains DMA + LDS, flips parities)
    }

    // ---- drain: G2(15) at parity 1 ----
#pragma unroll
    for (int kb = 0; kb < 4; ++kb) {
        bf16x8 bH = *(const bf16x8*)&LDSU[HB_OFF + HB_STR +
                        swz(mband * 32 + l31, KC, kb * 32 + lh * 16)];
#pragma unroll
        for (int ot = 0; ot < 2; ++ot) {
            bf16x8 aW2 = *(const bf16x8*)&LDSU[W2B_OFF + W2B_STR +
                            swz(ohalf * 64 + ot * 32 + l31, KC, kb * 32 + lh * 16)];
            acc2[ot] = __builtin_amdgcn_mfma_f32_32x32x16_bf16(aW2, bH, acc2[ot], 0, 0, 0);
        }
    }

    // ---- out: y[m][o] = acc2 + b2; o-quads -> float4 stores ----
    {
        int m = mband * 32 + l31;
#pragma unroll
        for (int ot = 0; ot < 2; ++ot)
#pragma unroll
            for (int rg = 0; rg < 4; ++rg) {
                int ob = ohalf * 64 + ot * 32 + rg * 8 + lh * 4;
                float4 b2f = *(const float4*)&b2[e * DO_ + ob];
                float4 val;
                val.x = acc2[ot][rg * 4 + 0] + b2f.x;
                val.y = acc2[ot][rg * 4 + 1] + b2f.y;
                val.z = acc2[ot][rg * 4 + 2] + b2f.z;
                val.w = acc2[ot][rg * 4 + 3] + b2f.w;
                *(float4*)&out[(size_t)(e * B_ + row0 + m) * DO_ + ob] = val;
            }
    }
}

extern "C" void kernel_launch(void* const* d_in, const int* in_sizes, int n_in,
                              void* d_out, int out_size, void* d_ws, size_t ws_size,
                              hipStream_t stream) {
    const float* x    = (const float*)d_in[0];
    const float* cond = (const float*)d_in[1];
    const float* W1   = (const float*)d_in[2];
    const float* b1   = (const float*)d_in[3];
    const float* W2   = (const float*)d_in[4];
    const float* b2   = (const float*)d_in[5];
    float* out = (float*)d_out;

    dim3 grid(E_ * (B_ / BM));   // 256 blocks = 1 per CU
    dim3 block(NT);

    const bool usews = (ws_size >= WS_BYTES) && (d_ws != nullptr);
    if (usews) {
        convert_w<<<2560, 256, 0, stream>>>((const float4*)W1, (const float4*)W2,
                                            (uint2*)d_ws);
        moe_fused_kernel<true><<<grid, block, 0, stream>>>(
            x, cond, W1, b1, W2, b2, (const uint2*)d_ws, out);
    } else {
        moe_fused_kernel<false><<<grid, block, 0, stream>>>(
            x, cond, W1, b1, W2, b2, (const uint2*)nullptr, out);
    }
}